// Round 1
// baseline (91.263 us; speedup 1.0000x reference)
//
#include <hip/hip_runtime.h>

#define B 16
#define F_DIM 256
#define P 8192
#define C 96
#define H 256
#define NSEG (B * C)          // 1536
#define ROWS 8                // rows per MLP block

// order-preserving float <-> uint mapping for atomicMax-based float max
__device__ __forceinline__ unsigned f2key(float x) {
    unsigned u = __float_as_uint(x);
    return (u & 0x80000000u) ? ~u : (u | 0x80000000u);
}
__device__ __forceinline__ float key2f(unsigned k) {
    unsigned u = (k & 0x80000000u) ? (k & 0x7FFFFFFFu) : ~k;
    return __uint_as_float(u);
}

__global__ __launch_bounds__(256) void count_kernel(const int* __restrict__ label,
                                                    int* __restrict__ counts) {
    __shared__ int hist[C];
    const int b = blockIdx.x;
    const int t = threadIdx.x;
    if (t < C) hist[t] = 0;
    __syncthreads();
    const int* lrow = label + b * P;
    for (int p = t; p < P; p += 256) {
        atomicAdd(&hist[lrow[p]], 1);
    }
    __syncthreads();
    if (t < C) counts[b * C + t] = hist[t];
}

// one block per (b, f): stream 8192 floats + labels, LDS atomicMax per class
__global__ __launch_bounds__(256) void pool_kernel(const float* __restrict__ feat,
                                                   const int* __restrict__ label,
                                                   const int* __restrict__ counts,
                                                   float* __restrict__ pooled) {
    __shared__ unsigned smax[C];
    const int blk = blockIdx.x;
    const int b = blk >> 8;       // / F_DIM
    const int f = blk & 255;      // % F_DIM
    const int t = threadIdx.x;
    if (t < C) smax[t] = 0u;      // key(-inf) > 0, so 0 is a safe identity
    __syncthreads();

    const float4* frow4 = (const float4*)(feat + ((size_t)b * F_DIM + f) * P);
    const int4*   lrow4 = (const int4*)(label + (size_t)b * P);
    for (int i = t; i < P / 4; i += 256) {
        float4 v = frow4[i];
        int4   c = lrow4[i];
        atomicMax(&smax[c.x], f2key(v.x));
        atomicMax(&smax[c.y], f2key(v.y));
        atomicMax(&smax[c.z], f2key(v.z));
        atomicMax(&smax[c.w], f2key(v.w));
    }
    __syncthreads();

    if (t < C) {
        const int cnt = counts[b * C + t];
        const float v = key2f(smax[t]);
        float r = (cnt == 0) ? 0.0f : ((cnt == P) ? v : fmaxf(v, 0.0f));
        pooled[(size_t)(b * C + t) * F_DIM + f] = r;
    }
}

// 8 rows per block; thread t owns output column t of each layer
__global__ __launch_bounds__(256) void mlp_kernel(const float* __restrict__ pooled,
                                                  const float* __restrict__ w1,
                                                  const float* __restrict__ b1,
                                                  const float* __restrict__ w2,
                                                  const float* __restrict__ b2,
                                                  const float* __restrict__ wl,
                                                  const float* __restrict__ bl,
                                                  float* __restrict__ out) {
    __shared__ float xs[ROWS][H];
    __shared__ float ys[ROWS][H];
    const int t = threadIdx.x;
    const int row0 = blockIdx.x * ROWS;

    #pragma unroll
    for (int r = 0; r < ROWS; ++r)
        xs[r][t] = pooled[(size_t)(row0 + r) * H + t];
    __syncthreads();

    float acc[ROWS];

    // layer 1: h = relu(x @ w1 + b1)
    {
        const float bias = b1[t];
        #pragma unroll
        for (int r = 0; r < ROWS; ++r) acc[r] = bias;
        for (int k = 0; k < H; ++k) {
            float wv = w1[k * H + t];
            #pragma unroll
            for (int r = 0; r < ROWS; ++r) acc[r] = fmaf(xs[r][k], wv, acc[r]);
        }
        #pragma unroll
        for (int r = 0; r < ROWS; ++r) ys[r][t] = fmaxf(acc[r], 0.0f);
    }
    __syncthreads();

    // layer 2: h = relu(h @ w2 + b2)  (reads ys, writes xs)
    {
        const float bias = b2[t];
        #pragma unroll
        for (int r = 0; r < ROWS; ++r) acc[r] = bias;
        for (int k = 0; k < H; ++k) {
            float wv = w2[k * H + t];
            #pragma unroll
            for (int r = 0; r < ROWS; ++r) acc[r] = fmaf(ys[r][k], wv, acc[r]);
        }
        #pragma unroll
        for (int r = 0; r < ROWS; ++r) xs[r][t] = fmaxf(acc[r], 0.0f);
    }
    __syncthreads();

    // logits: part_pred = h @ w_logit + b_logit   (96 columns)
    if (t < C) {
        float acc2[ROWS];
        const float bias = bl[t];
        #pragma unroll
        for (int r = 0; r < ROWS; ++r) acc2[r] = bias;
        for (int k = 0; k < H; ++k) {
            float wv = wl[k * C + t];
            #pragma unroll
            for (int r = 0; r < ROWS; ++r) acc2[r] = fmaf(xs[r][k], wv, acc2[r]);
        }
        #pragma unroll
        for (int r = 0; r < ROWS; ++r) out[(size_t)(row0 + r) * C + t] = acc2[r];
    }

    // part_label / part_batch tails (as float, matching float32 d_out)
    if (t < ROWS) {
        const int row = row0 + t;
        out[(size_t)NSEG * C + row] = (float)(row % C);
        out[(size_t)NSEG * C + NSEG + row] = (float)(row / C);
    }
}

extern "C" void kernel_launch(void* const* d_in, const int* in_sizes, int n_in,
                              void* d_out, int out_size, void* d_ws, size_t ws_size,
                              hipStream_t stream) {
    const float* feat  = (const float*)d_in[0];
    const int*   label = (const int*)d_in[1];
    const float* w1    = (const float*)d_in[2];
    const float* b1    = (const float*)d_in[3];
    const float* w2    = (const float*)d_in[4];
    const float* b2    = (const float*)d_in[5];
    const float* wl    = (const float*)d_in[6];
    const float* bl    = (const float*)d_in[7];
    float* out = (float*)d_out;

    int*   counts = (int*)d_ws;
    float* pooled = (float*)((char*)d_ws + ((NSEG * sizeof(int) + 255) / 256) * 256);

    count_kernel<<<B, 256, 0, stream>>>(label, counts);
    pool_kernel<<<B * F_DIM, 256, 0, stream>>>(feat, label, counts, pooled);
    mlp_kernel<<<NSEG / ROWS, 256, 0, stream>>>(pooled, w1, b1, w2, b2, wl, bl, out);
}